// Round 1
// baseline (702.086 us; speedup 1.0000x reference)
//
#include <hip/hip_runtime.h>
#include <hip/hip_bf16.h>

#define N_FEAT 8192
#define D_MODEL 256
#define HEADS 4
#define CELLS 32
#define BATCH 4096

typedef __attribute__((ext_vector_type(8))) short bf16x8;
typedef __attribute__((ext_vector_type(4))) float f32x4;

__device__ __forceinline__ unsigned short f32_to_bf16(float f) {
    union { float f; unsigned u; } v; v.f = f;
    unsigned r = v.u + 0x7fffu + ((v.u >> 16) & 1u);
    return (unsigned short)(r >> 16);
}

// ---------------------------------------------------------------------------
// Stage 1: reps[n,d] = proj[n,d] + sum_h ( g*cb[h,w] + (1-g)*cb[h,r] )[d]
// one block (256 thr) per feature row n
// ---------------------------------------------------------------------------
__global__ __launch_bounds__(256) void reps_kernel(
    const float* __restrict__ proj, const float* __restrict__ rw,
    const float* __restrict__ rb, const float* __restrict__ cb,
    unsigned short* __restrict__ reps_bf)
{
    __shared__ float lat[D_MODEL];
    __shared__ float sc[HEADS * CELLS];
    __shared__ float gateS[HEADS];
    __shared__ int widxS[HEADS], ridxS[HEADS];

    const int n = blockIdx.x;
    const int t = threadIdx.x;

    lat[t] = proj[(long)n * D_MODEL + t];
    __syncthreads();

    // tropical scores: 2 threads per (h,c), each over half of d
    {
        const int hc = t >> 1, hf = t & 1;
        const float* wrow = rw + (long)hc * D_MODEL + hf * 128;
        const float* lrow = lat + hf * 128;
        float m = -3.4e38f;
        #pragma unroll 8
        for (int d = 0; d < 128; ++d) m = fmaxf(m, lrow[d] + wrow[d]);
        float o = __shfl_xor(m, 1);
        m = fmaxf(m, o);
        if (hf == 0) sc[hc] = m + rb[hc];
    }
    __syncthreads();

    // top-2 per head
    if (t < HEADS) {
        float v1 = -3.4e38f, v2 = -3.4e38f; int i1 = 0, i2 = 0;
        for (int c = 0; c < CELLS; ++c) {
            float s = sc[t * CELLS + c];
            if (s > v1) { v2 = v1; i2 = i1; v1 = s; i1 = c; }
            else if (s > v2) { v2 = s; i2 = c; }
        }
        gateS[t] = 1.0f / (1.0f + __expf(-(v1 - v2)));
        widxS[t] = i1; ridxS[t] = i2;
    }
    __syncthreads();

    float r = lat[t];
    #pragma unroll
    for (int h = 0; h < HEADS; ++h) {
        const float g = gateS[h];
        const float wv = cb[((long)(h * CELLS + widxS[h])) * D_MODEL + t];
        const float rv = cb[((long)(h * CELLS + ridxS[h])) * D_MODEL + t];
        r += g * wv + (1.0f - g) * rv;   // CODE_SCALE = 1
    }
    reps_bf[(long)n * D_MODEL + t] = f32_to_bf16(r);
}

// ---------------------------------------------------------------------------
// Stage 1b: repsT[d][n] = reps[n][d]   (bf16, 256 x 8192)
// coalesced on write, scattered reads absorbed by L2/L3 (reps is 4 MB)
// ---------------------------------------------------------------------------
__global__ __launch_bounds__(256) void transpose_kernel(
    const unsigned short* __restrict__ reps, unsigned short* __restrict__ repsT)
{
    const int id = blockIdx.x * 256 + threadIdx.x;   // 2,097,152 total
    const int d = id >> 13;        // / 8192
    const int n = id & 8191;
    repsT[id] = reps[n * D_MODEL + d];
}

// ---------------------------------------------------------------------------
// Stage 2: hidden_part[ks] = x[:, ks-chunk] @ reps[ks-chunk, :]   (f32 out)
// 128x128 tile, 4 waves, 4x4 16x16x32 bf16 MFMA frags per wave, K-split x4
// x converted f32->bf16 during LDS staging
// ---------------------------------------------------------------------------
__global__ __launch_bounds__(256) void gemm1_kernel(
    const float* __restrict__ x, const unsigned short* __restrict__ repsT,
    float* __restrict__ hidden_part)
{
    __shared__ unsigned short As[128 * 32];
    __shared__ unsigned short Bs[128 * 32];

    const int m0 = blockIdx.y * 128;
    const int n0 = blockIdx.x * 128;
    const int ks = blockIdx.z;
    const int t = threadIdx.x;
    const int wave = t >> 6, lane = t & 63;
    const int wm = (wave >> 1) * 64, wn = (wave & 1) * 64;
    const int quad = lane >> 4, l16 = lane & 15;

    f32x4 acc[4][4];
    #pragma unroll
    for (int i = 0; i < 4; ++i)
        #pragma unroll
        for (int j = 0; j < 4; ++j)
            acc[i][j] = (f32x4){0.f, 0.f, 0.f, 0.f};

    const int row = t >> 1, hf = t & 1;
    const float* xsrc = x + (long)(m0 + row) * N_FEAT + hf * 16;
    const unsigned short* bsrc = repsT + (long)(n0 + row) * N_FEAT + hf * 16;
    unsigned short* aw = &As[row * 32 + hf * 16];
    unsigned short* bw = &Bs[row * 32 + hf * 16];

    const int kbeg = ks * 2048, kend = kbeg + 2048;
    for (int k0 = kbeg; k0 < kend; k0 += 32) {
        __syncthreads();
        // stage A (f32 -> bf16)
        {
            const float4* xs = (const float4*)(xsrc + k0);
            float4 f0 = xs[0], f1 = xs[1], f2 = xs[2], f3 = xs[3];
            float fv[16] = {f0.x, f0.y, f0.z, f0.w, f1.x, f1.y, f1.z, f1.w,
                            f2.x, f2.y, f2.z, f2.w, f3.x, f3.y, f3.z, f3.w};
            unsigned short tmp[16];
            #pragma unroll
            for (int i = 0; i < 16; ++i) tmp[i] = f32_to_bf16(fv[i]);
            *((uint4*)aw)       = *((const uint4*)tmp);
            *((uint4*)(aw + 8)) = *((const uint4*)(tmp + 8));
        }
        // stage B (bf16 passthrough)
        {
            const uint4* bs = (const uint4*)(bsrc + k0);
            uint4 b0 = bs[0], b1 = bs[1];
            *((uint4*)bw)       = b0;
            *((uint4*)(bw + 8)) = b1;
        }
        __syncthreads();

        bf16x8 af[4], bfr[4];
        #pragma unroll
        for (int i = 0; i < 4; ++i)
            af[i] = *((const bf16x8*)&As[(wm + i * 16 + l16) * 32 + quad * 8]);
        #pragma unroll
        for (int j = 0; j < 4; ++j)
            bfr[j] = *((const bf16x8*)&Bs[(wn + j * 16 + l16) * 32 + quad * 8]);
        #pragma unroll
        for (int i = 0; i < 4; ++i)
            #pragma unroll
            for (int j = 0; j < 4; ++j)
                acc[i][j] = __builtin_amdgcn_mfma_f32_16x16x32_bf16(
                    af[i], bfr[j], acc[i][j], 0, 0, 0);
    }

    float* hp = hidden_part + (long)ks * BATCH * D_MODEL;
    #pragma unroll
    for (int i = 0; i < 4; ++i)
        #pragma unroll
        for (int j = 0; j < 4; ++j) {
            const int col = n0 + wn + j * 16 + l16;
            #pragma unroll
            for (int r = 0; r < 4; ++r) {
                const int rowg = m0 + wm + i * 16 + quad * 4 + r;
                hp[(long)rowg * D_MODEL + col] = acc[i][j][r];
            }
        }
}

// ---------------------------------------------------------------------------
// Stage 2b: hidden_bf16 = bf16( sum of 4 K-split partials )
// ---------------------------------------------------------------------------
__global__ __launch_bounds__(256) void reduce_kernel(
    const float* __restrict__ hp, unsigned short* __restrict__ hb)
{
    const int id = blockIdx.x * 256 + threadIdx.x;   // over 262144 float4s
    const int S = BATCH * D_MODEL / 4;
    const float4* p = (const float4*)hp;
    float4 a = p[id], b = p[id + S], c = p[id + 2 * S], d = p[id + 3 * S];
    ushort4 o;
    o.x = f32_to_bf16(a.x + b.x + c.x + d.x);
    o.y = f32_to_bf16(a.y + b.y + c.y + d.y);
    o.z = f32_to_bf16(a.z + b.z + c.z + d.z);
    o.w = f32_to_bf16(a.w + b.w + c.w + d.w);
    ((ushort4*)hb)[id] = o;
}

// ---------------------------------------------------------------------------
// Stage 3: out = relu(hidden @ reps^T + bias)   M=4096 N=8192 K=256
// B^T is reps itself (row n, contiguous d)
// ---------------------------------------------------------------------------
__global__ __launch_bounds__(256) void gemm2_kernel(
    const unsigned short* __restrict__ hb, const unsigned short* __restrict__ reps,
    const float* __restrict__ bias, float* __restrict__ out)
{
    __shared__ unsigned short As[128 * 32];
    __shared__ unsigned short Bs[128 * 32];

    const int m0 = blockIdx.y * 128;   // batch
    const int n0 = blockIdx.x * 128;   // features
    const int t = threadIdx.x;
    const int wave = t >> 6, lane = t & 63;
    const int wm = (wave >> 1) * 64, wn = (wave & 1) * 64;
    const int quad = lane >> 4, l16 = lane & 15;

    f32x4 acc[4][4];
    #pragma unroll
    for (int i = 0; i < 4; ++i)
        #pragma unroll
        for (int j = 0; j < 4; ++j)
            acc[i][j] = (f32x4){0.f, 0.f, 0.f, 0.f};

    const int row = t >> 1, hf = t & 1;
    const unsigned short* asrc = hb + (long)(m0 + row) * D_MODEL + hf * 16;
    const unsigned short* bsrc = reps + (long)(n0 + row) * D_MODEL + hf * 16;
    unsigned short* aw = &As[row * 32 + hf * 16];
    unsigned short* bw = &Bs[row * 32 + hf * 16];

    for (int k0 = 0; k0 < D_MODEL; k0 += 32) {
        __syncthreads();
        {
            const uint4* as = (const uint4*)(asrc + k0);
            uint4 a0 = as[0], a1 = as[1];
            const uint4* bs = (const uint4*)(bsrc + k0);
            uint4 b0 = bs[0], b1 = bs[1];
            *((uint4*)aw)       = a0;
            *((uint4*)(aw + 8)) = a1;
            *((uint4*)bw)       = b0;
            *((uint4*)(bw + 8)) = b1;
        }
        __syncthreads();

        bf16x8 af[4], bfr[4];
        #pragma unroll
        for (int i = 0; i < 4; ++i)
            af[i] = *((const bf16x8*)&As[(wm + i * 16 + l16) * 32 + quad * 8]);
        #pragma unroll
        for (int j = 0; j < 4; ++j)
            bfr[j] = *((const bf16x8*)&Bs[(wn + j * 16 + l16) * 32 + quad * 8]);
        #pragma unroll
        for (int i = 0; i < 4; ++i)
            #pragma unroll
            for (int j = 0; j < 4; ++j)
                acc[i][j] = __builtin_amdgcn_mfma_f32_16x16x32_bf16(
                    af[i], bfr[j], acc[i][j], 0, 0, 0);
    }

    #pragma unroll
    for (int i = 0; i < 4; ++i)
        #pragma unroll
        for (int j = 0; j < 4; ++j) {
            const int col = n0 + wn + j * 16 + l16;
            const float bv = bias[col];
            #pragma unroll
            for (int r = 0; r < 4; ++r) {
                const int rowg = m0 + wm + i * 16 + quad * 4 + r;
                out[(long)rowg * N_FEAT + col] = fmaxf(acc[i][j][r] + bv, 0.f);
            }
        }
}

// ---------------------------------------------------------------------------
extern "C" void kernel_launch(void* const* d_in, const int* in_sizes, int n_in,
                              void* d_out, int out_size, void* d_ws, size_t ws_size,
                              hipStream_t stream) {
    const float* x    = (const float*)d_in[0];
    const float* proj = (const float*)d_in[1];
    const float* rw   = (const float*)d_in[2];
    const float* rb   = (const float*)d_in[3];
    const float* cb   = (const float*)d_in[4];
    const float* bias = (const float*)d_in[5];
    float* out = (float*)d_out;

    char* ws = (char*)d_ws;
    unsigned short* reps_bf = (unsigned short*)ws;                 // 4 MB
    unsigned short* repsT   = (unsigned short*)(ws + (4u << 20));  // 4 MB
    float* hidden_part      = (float*)(ws + (8u << 20));           // 16 MB
    unsigned short* hid_bf  = (unsigned short*)(ws + (24u << 20)); // 2 MB

    reps_kernel<<<N_FEAT, 256, 0, stream>>>(proj, rw, rb, cb, reps_bf);
    transpose_kernel<<<N_FEAT, 256, 0, stream>>>(reps_bf, repsT);
    gemm1_kernel<<<dim3(2, 32, 4), 256, 0, stream>>>(x, repsT, hidden_part);
    reduce_kernel<<<1024, 256, 0, stream>>>(hidden_part, hid_bf);
    gemm2_kernel<<<dim3(64, 32), 256, 0, stream>>>(hid_bf, reps_bf, bias, out);
}

// Round 2
// 360.974 us; speedup vs baseline: 1.9450x; 1.9450x over previous
//
#include <hip/hip_runtime.h>
#include <hip/hip_bf16.h>

#define N_FEAT 8192
#define D_MODEL 256
#define HEADS 4
#define CELLS 32
#define BATCH 4096
#define HC 128          // HEADS*CELLS
#define NT 32           // n-rows per reps block
#define DC 64           // d-chunk

typedef __attribute__((ext_vector_type(8))) short bf16x8;
typedef __attribute__((ext_vector_type(4))) float f32x4;

__device__ __forceinline__ unsigned short f32_to_bf16(float f) {
    union { float f; unsigned u; } v; v.f = f;
    unsigned r = v.u + 0x7fffu + ((v.u >> 16) & 1u);
    return (unsigned short)(r >> 16);
}

// ---------------------------------------------------------------------------
// Stage 1 (fused): tropical scores (tiled max-plus GEMM) -> top-2 -> sigmoid
// blend -> write reps (bf16) AND repsT (bf16), one block per 32 feature rows.
// ---------------------------------------------------------------------------
__global__ __launch_bounds__(256) void reps_kernel(
    const float* __restrict__ proj, const float* __restrict__ rw,
    const float* __restrict__ rb, const float* __restrict__ cb,
    unsigned short* __restrict__ reps_bf, unsigned short* __restrict__ repsT)
{
    __shared__ float latS[NT][DC + 4];     // stride 68
    __shared__ float wS[HC][DC + 4];       // stride 68
    __shared__ float sc[NT][HC + 4];       // stride 132
    __shared__ float T[NT][257];           // conflict-free transpose tile
    __shared__ float gateS[NT][HEADS];
    __shared__ int   widxS[NT][HEADS], ridxS[NT][HEADS];

    const int t = threadIdx.x;
    const int nbase = blockIdx.x * NT;
    const int tx = t & 31, ty = t >> 5;    // tx -> hc groups, ty -> n groups
    const int hc0 = tx * 4, n0 = ty * 4;

    float acc[4][4];
    #pragma unroll
    for (int i = 0; i < 4; ++i)
        #pragma unroll
        for (int j = 0; j < 4; ++j)
            acc[i][j] = -3.4e38f;

    // ---- tiled max-plus scores ----
    for (int dk = 0; dk < D_MODEL; dk += DC) {
        __syncthreads();
        // stage lat chunk: 32 x 64 f32 = 512 float4, 2 per thread
        {
            int f = t;
            #pragma unroll
            for (int i = 0; i < 2; ++i, f += 256) {
                const int row = f >> 4, c4 = f & 15;
                float4 v = *(const float4*)&proj[(long)(nbase + row) * D_MODEL + dk + c4 * 4];
                *(float4*)&latS[row][c4 * 4] = v;
            }
        }
        // stage W chunk: 128 x 64 f32 = 2048 float4, 8 per thread
        {
            int f = t;
            #pragma unroll
            for (int i = 0; i < 8; ++i, f += 256) {
                const int row = f >> 4, c4 = f & 15;
                float4 v = *(const float4*)&rw[(long)row * D_MODEL + dk + c4 * 4];
                *(float4*)&wS[row][c4 * 4] = v;
            }
        }
        __syncthreads();

        #pragma unroll 4
        for (int d = 0; d < DC; d += 4) {
            float4 la[4], wv[4];
            #pragma unroll
            for (int i = 0; i < 4; ++i) la[i] = *(const float4*)&latS[n0 + i][d];
            #pragma unroll
            for (int j = 0; j < 4; ++j) wv[j] = *(const float4*)&wS[hc0 + j][d];
            #pragma unroll
            for (int i = 0; i < 4; ++i)
                #pragma unroll
                for (int j = 0; j < 4; ++j) {
                    float m01 = fmaxf(la[i].x + wv[j].x, la[i].y + wv[j].y);
                    float m23 = fmaxf(la[i].z + wv[j].z, la[i].w + wv[j].w);
                    acc[i][j] = fmaxf(acc[i][j], fmaxf(m01, m23));
                }
        }
    }

    // scores (+router bias) to LDS
    #pragma unroll
    for (int j = 0; j < 4; ++j) {
        const float rbv = rb[hc0 + j];
        #pragma unroll
        for (int i = 0; i < 4; ++i)
            sc[n0 + i][hc0 + j] = acc[i][j] + rbv;
    }
    __syncthreads();

    // ---- top-2 per (n, h): 128 tasks ----
    if (t < NT * HEADS) {
        const int n = t >> 2, h = t & 3;
        float v1 = -3.4e38f, v2 = -3.4e38f; int i1 = 0, i2 = 0;
        #pragma unroll
        for (int c = 0; c < CELLS; ++c) {
            float s = sc[n][h * CELLS + c];
            if (s > v1) { v2 = v1; i2 = i1; v1 = s; i1 = c; }
            else if (s > v2) { v2 = s; i2 = c; }
        }
        gateS[n][h] = 1.0f / (1.0f + __expf(-(v1 - v2)));
        widxS[n][h] = i1; ridxS[n][h] = i2;
    }
    __syncthreads();

    // ---- blend + write reps_bf, stash float tile for transpose ----
    #pragma unroll 4
    for (int r = 0; r < NT; ++r) {
        float val = proj[(long)(nbase + r) * D_MODEL + t];
        #pragma unroll
        for (int h = 0; h < HEADS; ++h) {
            const float g = gateS[r][h];
            const float wv = cb[(long)(h * CELLS + widxS[r][h]) * D_MODEL + t];
            const float rv = cb[(long)(h * CELLS + ridxS[r][h]) * D_MODEL + t];
            val += g * wv + (1.0f - g) * rv;   // CODE_SCALE = 1
        }
        reps_bf[(long)(nbase + r) * D_MODEL + t] = f32_to_bf16(val);
        T[r][t] = val;
    }
    __syncthreads();

    // ---- write repsT[d][n] (bf16): conflict-free LDS reads, 64B row writes
    #pragma unroll
    for (int i = 0; i < 32; ++i) {
        const int d = i * 8 + (t >> 5);
        const int n = t & 31;
        repsT[(long)d * N_FEAT + nbase + n] = f32_to_bf16(T[n][d]);
    }
}

// ---------------------------------------------------------------------------
// Stage 2: hidden_part[ks] = x[:, ks-chunk] @ reps[ks-chunk, :]   (f32 out)
// 128x128 tile, 4 waves, 4x4 16x16x32 bf16 MFMA frags per wave, K-split x4
// x converted f32->bf16 during LDS staging
// ---------------------------------------------------------------------------
__global__ __launch_bounds__(256) void gemm1_kernel(
    const float* __restrict__ x, const unsigned short* __restrict__ repsT,
    float* __restrict__ hidden_part)
{
    __shared__ unsigned short As[128 * 32];
    __shared__ unsigned short Bs[128 * 32];

    const int m0 = blockIdx.y * 128;
    const int n0 = blockIdx.x * 128;
    const int ks = blockIdx.z;
    const int t = threadIdx.x;
    const int wave = t >> 6, lane = t & 63;
    const int wm = (wave >> 1) * 64, wn = (wave & 1) * 64;
    const int quad = lane >> 4, l16 = lane & 15;

    f32x4 acc[4][4];
    #pragma unroll
    for (int i = 0; i < 4; ++i)
        #pragma unroll
        for (int j = 0; j < 4; ++j)
            acc[i][j] = (f32x4){0.f, 0.f, 0.f, 0.f};

    const int row = t >> 1, hf = t & 1;
    const float* xsrc = x + (long)(m0 + row) * N_FEAT + hf * 16;
    const unsigned short* bsrc = repsT + (long)(n0 + row) * N_FEAT + hf * 16;
    unsigned short* aw = &As[row * 32 + hf * 16];
    unsigned short* bw = &Bs[row * 32 + hf * 16];

    const int kbeg = ks * 2048, kend = kbeg + 2048;
    for (int k0 = kbeg; k0 < kend; k0 += 32) {
        __syncthreads();
        // stage A (f32 -> bf16)
        {
            const float4* xs = (const float4*)(xsrc + k0);
            float4 f0 = xs[0], f1 = xs[1], f2 = xs[2], f3 = xs[3];
            float fv[16] = {f0.x, f0.y, f0.z, f0.w, f1.x, f1.y, f1.z, f1.w,
                            f2.x, f2.y, f2.z, f2.w, f3.x, f3.y, f3.z, f3.w};
            unsigned short tmp[16];
            #pragma unroll
            for (int i = 0; i < 16; ++i) tmp[i] = f32_to_bf16(fv[i]);
            *((uint4*)aw)       = *((const uint4*)tmp);
            *((uint4*)(aw + 8)) = *((const uint4*)(tmp + 8));
        }
        // stage B (bf16 passthrough)
        {
            const uint4* bs = (const uint4*)(bsrc + k0);
            uint4 b0 = bs[0], b1 = bs[1];
            *((uint4*)bw)       = b0;
            *((uint4*)(bw + 8)) = b1;
        }
        __syncthreads();

        bf16x8 af[4], bfr[4];
        #pragma unroll
        for (int i = 0; i < 4; ++i)
            af[i] = *((const bf16x8*)&As[(wm + i * 16 + l16) * 32 + quad * 8]);
        #pragma unroll
        for (int j = 0; j < 4; ++j)
            bfr[j] = *((const bf16x8*)&Bs[(wn + j * 16 + l16) * 32 + quad * 8]);
        #pragma unroll
        for (int i = 0; i < 4; ++i)
            #pragma unroll
            for (int j = 0; j < 4; ++j)
                acc[i][j] = __builtin_amdgcn_mfma_f32_16x16x32_bf16(
                    af[i], bfr[j], acc[i][j], 0, 0, 0);
    }

    float* hp = hidden_part + (long)ks * BATCH * D_MODEL;
    #pragma unroll
    for (int i = 0; i < 4; ++i)
        #pragma unroll
        for (int j = 0; j < 4; ++j) {
            const int col = n0 + wn + j * 16 + l16;
            #pragma unroll
            for (int r = 0; r < 4; ++r) {
                const int rowg = m0 + wm + i * 16 + quad * 4 + r;
                hp[(long)rowg * D_MODEL + col] = acc[i][j][r];
            }
        }
}

// ---------------------------------------------------------------------------
// Stage 2b: hidden_bf16 = bf16( sum of 4 K-split partials )
// ---------------------------------------------------------------------------
__global__ __launch_bounds__(256) void reduce_kernel(
    const float* __restrict__ hp, unsigned short* __restrict__ hb)
{
    const int id = blockIdx.x * 256 + threadIdx.x;   // over 262144 float4s
    const int S = BATCH * D_MODEL / 4;
    const float4* p = (const float4*)hp;
    float4 a = p[id], b = p[id + S], c = p[id + 2 * S], d = p[id + 3 * S];
    ushort4 o;
    o.x = f32_to_bf16(a.x + b.x + c.x + d.x);
    o.y = f32_to_bf16(a.y + b.y + c.y + d.y);
    o.z = f32_to_bf16(a.z + b.z + c.z + d.z);
    o.w = f32_to_bf16(a.w + b.w + c.w + d.w);
    ((ushort4*)hb)[id] = o;
}

// ---------------------------------------------------------------------------
// Stage 3: out = relu(hidden @ reps^T + bias)   M=4096 N=8192 K=256
// B^T is reps itself (row n, contiguous d)
// ---------------------------------------------------------------------------
__global__ __launch_bounds__(256) void gemm2_kernel(
    const unsigned short* __restrict__ hb, const unsigned short* __restrict__ reps,
    const float* __restrict__ bias, float* __restrict__ out)
{
    __shared__ unsigned short As[128 * 32];
    __shared__ unsigned short Bs[128 * 32];

    const int m0 = blockIdx.y * 128;   // batch
    const int n0 = blockIdx.x * 128;   // features
    const int t = threadIdx.x;
    const int wave = t >> 6, lane = t & 63;
    const int wm = (wave >> 1) * 64, wn = (wave & 1) * 64;
    const int quad = lane >> 4, l16 = lane & 15;

    f32x4 acc[4][4];
    #pragma unroll
    for (int i = 0; i < 4; ++i)
        #pragma unroll
        for (int j = 0; j < 4; ++j)
            acc[i][j] = (f32x4){0.f, 0.f, 0.f, 0.f};

    const int row = t >> 1, hf = t & 1;
    const unsigned short* asrc = hb + (long)(m0 + row) * D_MODEL + hf * 16;
    const unsigned short* bsrc = reps + (long)(n0 + row) * D_MODEL + hf * 16;
    unsigned short* aw = &As[row * 32 + hf * 16];
    unsigned short* bw = &Bs[row * 32 + hf * 16];

    for (int k0 = 0; k0 < D_MODEL; k0 += 32) {
        __syncthreads();
        {
            const uint4* as = (const uint4*)(asrc + k0);
            uint4 a0 = as[0], a1 = as[1];
            const uint4* bs = (const uint4*)(bsrc + k0);
            uint4 b0 = bs[0], b1 = bs[1];
            *((uint4*)aw)       = a0;
            *((uint4*)(aw + 8)) = a1;
            *((uint4*)bw)       = b0;
            *((uint4*)(bw + 8)) = b1;
        }
        __syncthreads();

        bf16x8 af[4], bfr[4];
        #pragma unroll
        for (int i = 0; i < 4; ++i)
            af[i] = *((const bf16x8*)&As[(wm + i * 16 + l16) * 32 + quad * 8]);
        #pragma unroll
        for (int j = 0; j < 4; ++j)
            bfr[j] = *((const bf16x8*)&Bs[(wn + j * 16 + l16) * 32 + quad * 8]);
        #pragma unroll
        for (int i = 0; i < 4; ++i)
            #pragma unroll
            for (int j = 0; j < 4; ++j)
                acc[i][j] = __builtin_amdgcn_mfma_f32_16x16x32_bf16(
                    af[i], bfr[j], acc[i][j], 0, 0, 0);
    }

    #pragma unroll
    for (int i = 0; i < 4; ++i)
        #pragma unroll
        for (int j = 0; j < 4; ++j) {
            const int col = n0 + wn + j * 16 + l16;
            const float bv = bias[col];
            #pragma unroll
            for (int r = 0; r < 4; ++r) {
                const int rowg = m0 + wm + i * 16 + quad * 4 + r;
                out[(long)rowg * N_FEAT + col] = fmaxf(acc[i][j][r] + bv, 0.f);
            }
        }
}

// ---------------------------------------------------------------------------
extern "C" void kernel_launch(void* const* d_in, const int* in_sizes, int n_in,
                              void* d_out, int out_size, void* d_ws, size_t ws_size,
                              hipStream_t stream) {
    const float* x    = (const float*)d_in[0];
    const float* proj = (const float*)d_in[1];
    const float* rw   = (const float*)d_in[2];
    const float* rb   = (const float*)d_in[3];
    const float* cb   = (const float*)d_in[4];
    const float* bias = (const float*)d_in[5];
    float* out = (float*)d_out;

    char* ws = (char*)d_ws;
    unsigned short* reps_bf = (unsigned short*)ws;                 // 4 MB
    unsigned short* repsT   = (unsigned short*)(ws + (4u << 20));  // 4 MB
    float* hidden_part      = (float*)(ws + (8u << 20));           // 16 MB
    unsigned short* hid_bf  = (unsigned short*)(ws + (24u << 20)); // 2 MB

    reps_kernel<<<N_FEAT / NT, 256, 0, stream>>>(proj, rw, rb, cb, reps_bf, repsT);
    gemm1_kernel<<<dim3(2, 32, 4), 256, 0, stream>>>(x, repsT, hidden_part);
    reduce_kernel<<<1024, 256, 0, stream>>>(hidden_part, hid_bf);
    gemm2_kernel<<<dim3(64, 32), 256, 0, stream>>>(hid_bf, reps_bf, bias, out);
}

// Round 3
// 329.210 us; speedup vs baseline: 2.1326x; 1.0965x over previous
//
#include <hip/hip_runtime.h>
#include <hip/hip_bf16.h>

#define N_FEAT 8192
#define D_MODEL 256
#define HEADS 4
#define CELLS 32
#define BATCH 4096
#define HC 128          // HEADS*CELLS
#define NT 32           // n-rows per reps block
#define DC 64           // d-chunk
#define KSPLIT 16
#define KCH (N_FEAT / KSPLIT)   // 512

typedef __attribute__((ext_vector_type(8))) short bf16x8;
typedef __attribute__((ext_vector_type(4))) float f32x4;

__device__ __forceinline__ unsigned short f32_to_bf16(float f) {
    union { float f; unsigned u; } v; v.f = f;
    unsigned r = v.u + 0x7fffu + ((v.u >> 16) & 1u);
    return (unsigned short)(r >> 16);
}

__device__ __forceinline__ float bf16_to_f32(unsigned short h) {
    union { unsigned u; float f; } v; v.u = ((unsigned)h) << 16;
    return v.f;
}

// ---------------------------------------------------------------------------
// Stage 1 (fused): tropical scores (tiled max-plus GEMM) -> top-2 -> sigmoid
// blend -> write reps (bf16) AND repsT (bf16), one block per 32 feature rows.
// ---------------------------------------------------------------------------
__global__ __launch_bounds__(256) void reps_kernel(
    const float* __restrict__ proj, const float* __restrict__ rw,
    const float* __restrict__ rb, const float* __restrict__ cb,
    unsigned short* __restrict__ reps_bf, unsigned short* __restrict__ repsT)
{
    __shared__ float latS[NT][DC + 4];
    __shared__ float wS[HC][DC + 4];
    __shared__ float sc[NT][HC + 4];
    __shared__ float T[NT][257];
    __shared__ float gateS[NT][HEADS];
    __shared__ int   widxS[NT][HEADS], ridxS[NT][HEADS];

    const int t = threadIdx.x;
    const int nbase = blockIdx.x * NT;
    const int tx = t & 31, ty = t >> 5;
    const int hc0 = tx * 4, n0 = ty * 4;

    float acc[4][4];
    #pragma unroll
    for (int i = 0; i < 4; ++i)
        #pragma unroll
        for (int j = 0; j < 4; ++j)
            acc[i][j] = -3.4e38f;

    for (int dk = 0; dk < D_MODEL; dk += DC) {
        __syncthreads();
        {
            int f = t;
            #pragma unroll
            for (int i = 0; i < 2; ++i, f += 256) {
                const int row = f >> 4, c4 = f & 15;
                float4 v = *(const float4*)&proj[(long)(nbase + row) * D_MODEL + dk + c4 * 4];
                *(float4*)&latS[row][c4 * 4] = v;
            }
        }
        {
            int f = t;
            #pragma unroll
            for (int i = 0; i < 8; ++i, f += 256) {
                const int row = f >> 4, c4 = f & 15;
                float4 v = *(const float4*)&rw[(long)row * D_MODEL + dk + c4 * 4];
                *(float4*)&wS[row][c4 * 4] = v;
            }
        }
        __syncthreads();

        #pragma unroll 4
        for (int d = 0; d < DC; d += 4) {
            float4 la[4], wv[4];
            #pragma unroll
            for (int i = 0; i < 4; ++i) la[i] = *(const float4*)&latS[n0 + i][d];
            #pragma unroll
            for (int j = 0; j < 4; ++j) wv[j] = *(const float4*)&wS[hc0 + j][d];
            #pragma unroll
            for (int i = 0; i < 4; ++i)
                #pragma unroll
                for (int j = 0; j < 4; ++j) {
                    float m01 = fmaxf(la[i].x + wv[j].x, la[i].y + wv[j].y);
                    float m23 = fmaxf(la[i].z + wv[j].z, la[i].w + wv[j].w);
                    acc[i][j] = fmaxf(acc[i][j], fmaxf(m01, m23));
                }
        }
    }

    #pragma unroll
    for (int j = 0; j < 4; ++j) {
        const float rbv = rb[hc0 + j];
        #pragma unroll
        for (int i = 0; i < 4; ++i)
            sc[n0 + i][hc0 + j] = acc[i][j] + rbv;
    }
    __syncthreads();

    if (t < NT * HEADS) {
        const int n = t >> 2, h = t & 3;
        float v1 = -3.4e38f, v2 = -3.4e38f; int i1 = 0, i2 = 0;
        #pragma unroll
        for (int c = 0; c < CELLS; ++c) {
            float s = sc[n][h * CELLS + c];
            if (s > v1) { v2 = v1; i2 = i1; v1 = s; i1 = c; }
            else if (s > v2) { v2 = s; i2 = c; }
        }
        gateS[n][h] = 1.0f / (1.0f + __expf(-(v1 - v2)));
        widxS[n][h] = i1; ridxS[n][h] = i2;
    }
    __syncthreads();

    #pragma unroll 4
    for (int r = 0; r < NT; ++r) {
        float val = proj[(long)(nbase + r) * D_MODEL + t];
        #pragma unroll
        for (int h = 0; h < HEADS; ++h) {
            const float g = gateS[r][h];
            const float wv = cb[(long)(h * CELLS + widxS[r][h]) * D_MODEL + t];
            const float rv = cb[(long)(h * CELLS + ridxS[r][h]) * D_MODEL + t];
            val += g * wv + (1.0f - g) * rv;   // CODE_SCALE = 1
        }
        reps_bf[(long)(nbase + r) * D_MODEL + t] = f32_to_bf16(val);
        T[r][t] = val;
    }
    __syncthreads();

    #pragma unroll
    for (int i = 0; i < 32; ++i) {
        const int d = i * 8 + (t >> 5);
        const int n = t & 31;
        repsT[(long)d * N_FEAT + nbase + n] = f32_to_bf16(T[n][d]);
    }
}

// ---------------------------------------------------------------------------
// Stage 2: hidden_part[ks] = x[:, ks-chunk] @ reps[ks-chunk, :]  (bf16 out)
// 128x128 tile, 4 waves, 4x4 16x16x32 bf16 MFMA, K-split x16, reg-prefetch
// x converted f32->bf16 during LDS staging
// ---------------------------------------------------------------------------
__global__ __launch_bounds__(256, 4) void gemm1_kernel(
    const float* __restrict__ x, const unsigned short* __restrict__ repsT,
    unsigned short* __restrict__ hidden_part)
{
    __shared__ unsigned short As[128 * 32];
    __shared__ unsigned short Bs[128 * 32];

    const int m0 = blockIdx.y * 128;
    const int n0 = blockIdx.x * 128;
    const int ks = blockIdx.z;
    const int t = threadIdx.x;
    const int wave = t >> 6, lane = t & 63;
    const int wm = (wave >> 1) * 64, wn = (wave & 1) * 64;
    const int quad = lane >> 4, l16 = lane & 15;

    f32x4 acc[4][4];
    #pragma unroll
    for (int i = 0; i < 4; ++i)
        #pragma unroll
        for (int j = 0; j < 4; ++j)
            acc[i][j] = (f32x4){0.f, 0.f, 0.f, 0.f};

    const int row = t >> 1, hf = t & 1;
    const float* xsrc = x + (long)(m0 + row) * N_FEAT + hf * 16;
    const unsigned short* bsrc = repsT + (long)(n0 + row) * N_FEAT + hf * 16;
    unsigned short* aw = &As[row * 32 + hf * 16];
    unsigned short* bw = &Bs[row * 32 + hf * 16];

    const int kbeg = ks * KCH, kend = kbeg + KCH;

    // prefetch iter 0
    float4 fa[4]; uint4 fb[2];
    {
        const float4* xs = (const float4*)(xsrc + kbeg);
        fa[0] = xs[0]; fa[1] = xs[1]; fa[2] = xs[2]; fa[3] = xs[3];
        const uint4* bs = (const uint4*)(bsrc + kbeg);
        fb[0] = bs[0]; fb[1] = bs[1];
    }

    for (int k0 = kbeg; k0 < kend; k0 += 32) {
        // convert prefetched A regs (vmcnt wait lands here, after prev MFMAs)
        unsigned short tmp[16];
        {
            float fv[16] = {fa[0].x, fa[0].y, fa[0].z, fa[0].w,
                            fa[1].x, fa[1].y, fa[1].z, fa[1].w,
                            fa[2].x, fa[2].y, fa[2].z, fa[2].w,
                            fa[3].x, fa[3].y, fa[3].z, fa[3].w};
            #pragma unroll
            for (int i = 0; i < 16; ++i) tmp[i] = f32_to_bf16(fv[i]);
        }
        uint4 b0 = fb[0], b1 = fb[1];
        __syncthreads();
        *((uint4*)aw)       = *((const uint4*)tmp);
        *((uint4*)(aw + 8)) = *((const uint4*)(tmp + 8));
        *((uint4*)bw)       = b0;
        *((uint4*)(bw + 8)) = b1;
        __syncthreads();

        // issue next iter's loads — overlap with MFMA phase below
        if (k0 + 32 < kend) {
            const float4* xs = (const float4*)(xsrc + k0 + 32);
            fa[0] = xs[0]; fa[1] = xs[1]; fa[2] = xs[2]; fa[3] = xs[3];
            const uint4* bs = (const uint4*)(bsrc + k0 + 32);
            fb[0] = bs[0]; fb[1] = bs[1];
        }

        bf16x8 af[4], bfr[4];
        #pragma unroll
        for (int i = 0; i < 4; ++i)
            af[i] = *((const bf16x8*)&As[(wm + i * 16 + l16) * 32 + quad * 8]);
        #pragma unroll
        for (int j = 0; j < 4; ++j)
            bfr[j] = *((const bf16x8*)&Bs[(wn + j * 16 + l16) * 32 + quad * 8]);
        #pragma unroll
        for (int i = 0; i < 4; ++i)
            #pragma unroll
            for (int j = 0; j < 4; ++j)
                acc[i][j] = __builtin_amdgcn_mfma_f32_16x16x32_bf16(
                    af[i], bfr[j], acc[i][j], 0, 0, 0);
    }

    unsigned short* hp = hidden_part + (long)ks * BATCH * D_MODEL;
    #pragma unroll
    for (int i = 0; i < 4; ++i)
        #pragma unroll
        for (int j = 0; j < 4; ++j) {
            const int col = n0 + wn + j * 16 + l16;
            #pragma unroll
            for (int r = 0; r < 4; ++r) {
                const int rowg = m0 + wm + i * 16 + quad * 4 + r;
                hp[(long)rowg * D_MODEL + col] = f32_to_bf16(acc[i][j][r]);
            }
        }
}

// ---------------------------------------------------------------------------
// Stage 2b: hidden_bf16 = bf16( sum of 16 bf16 K-split partials )
// ---------------------------------------------------------------------------
__global__ __launch_bounds__(256) void reduce_kernel(
    const unsigned short* __restrict__ hp, unsigned short* __restrict__ hb)
{
    const int id = blockIdx.x * 256 + threadIdx.x;   // over 131072 uint4 (8 bf16)
    const int S = BATCH * D_MODEL / 8;
    const uint4* p = (const uint4*)hp;
    float s[8] = {0.f, 0.f, 0.f, 0.f, 0.f, 0.f, 0.f, 0.f};
    #pragma unroll
    for (int k = 0; k < KSPLIT; ++k) {
        uint4 v = p[(long)k * S + id];
        unsigned short e[8];
        *(uint4*)e = v;
        #pragma unroll
        for (int j = 0; j < 8; ++j) s[j] += bf16_to_f32(e[j]);
    }
    unsigned short o[8];
    #pragma unroll
    for (int j = 0; j < 8; ++j) o[j] = f32_to_bf16(s[j]);
    ((uint4*)hb)[id] = *(const uint4*)o;
}

// ---------------------------------------------------------------------------
// Stage 3: out = relu(hidden @ reps^T + bias)   M=4096 N=8192 K=256
// B^T is reps itself (row n, contiguous d); reg-prefetch pipeline
// ---------------------------------------------------------------------------
__global__ __launch_bounds__(256, 4) void gemm2_kernel(
    const unsigned short* __restrict__ hb, const unsigned short* __restrict__ reps,
    const float* __restrict__ bias, float* __restrict__ out)
{
    __shared__ unsigned short As[128 * 32];
    __shared__ unsigned short Bs[128 * 32];

    const int m0 = blockIdx.y * 128;   // batch
    const int n0 = blockIdx.x * 128;   // features
    const int t = threadIdx.x;
    const int wave = t >> 6, lane = t & 63;
    const int wm = (wave >> 1) * 64, wn = (wave & 1) * 64;
    const int quad = lane >> 4, l16 = lane & 15;

    f32x4 acc[4][4];
    #pragma unroll
    for (int i = 0; i < 4; ++i)
        #pragma unroll
        for (int j = 0; j < 4; ++j)
            acc[i][j] = (f32x4){0.f, 0.f, 0.f, 0.f};

    const int row = t >> 1, hf = t & 1;
    const unsigned short* asrc = hb + (long)(m0 + row) * D_MODEL + hf * 16;
    const unsigned short* bsrc = reps + (long)(n0 + row) * D_MODEL + hf * 16;
    unsigned short* aw = &As[row * 32 + hf * 16];
    unsigned short* bw = &Bs[row * 32 + hf * 16];

    uint4 pa0, pa1, pb0, pb1;
    {
        const uint4* as = (const uint4*)(asrc);
        pa0 = as[0]; pa1 = as[1];
        const uint4* bs = (const uint4*)(bsrc);
        pb0 = bs[0]; pb1 = bs[1];
    }

    for (int k0 = 0; k0 < D_MODEL; k0 += 32) {
        uint4 a0 = pa0, a1 = pa1, b0 = pb0, b1 = pb1;
        __syncthreads();
        *((uint4*)aw)       = a0;
        *((uint4*)(aw + 8)) = a1;
        *((uint4*)bw)       = b0;
        *((uint4*)(bw + 8)) = b1;
        __syncthreads();

        if (k0 + 32 < D_MODEL) {
            const uint4* as = (const uint4*)(asrc + k0 + 32);
            pa0 = as[0]; pa1 = as[1];
            const uint4* bs = (const uint4*)(bsrc + k0 + 32);
            pb0 = bs[0]; pb1 = bs[1];
        }

        bf16x8 af[4], bfr[4];
        #pragma unroll
        for (int i = 0; i < 4; ++i)
            af[i] = *((const bf16x8*)&As[(wm + i * 16 + l16) * 32 + quad * 8]);
        #pragma unroll
        for (int j = 0; j < 4; ++j)
            bfr[j] = *((const bf16x8*)&Bs[(wn + j * 16 + l16) * 32 + quad * 8]);
        #pragma unroll
        for (int i = 0; i < 4; ++i)
            #pragma unroll
            for (int j = 0; j < 4; ++j)
                acc[i][j] = __builtin_amdgcn_mfma_f32_16x16x32_bf16(
                    af[i], bfr[j], acc[i][j], 0, 0, 0);
    }

    #pragma unroll
    for (int i = 0; i < 4; ++i)
        #pragma unroll
        for (int j = 0; j < 4; ++j) {
            const int col = n0 + wn + j * 16 + l16;
            const float bv = bias[col];
            #pragma unroll
            for (int r = 0; r < 4; ++r) {
                const int rowg = m0 + wm + i * 16 + quad * 4 + r;
                out[(long)rowg * N_FEAT + col] = fmaxf(acc[i][j][r] + bv, 0.f);
            }
        }
}

// ---------------------------------------------------------------------------
extern "C" void kernel_launch(void* const* d_in, const int* in_sizes, int n_in,
                              void* d_out, int out_size, void* d_ws, size_t ws_size,
                              hipStream_t stream) {
    const float* x    = (const float*)d_in[0];
    const float* proj = (const float*)d_in[1];
    const float* rw   = (const float*)d_in[2];
    const float* rb   = (const float*)d_in[3];
    const float* cb   = (const float*)d_in[4];
    const float* bias = (const float*)d_in[5];
    float* out = (float*)d_out;

    char* ws = (char*)d_ws;
    unsigned short* reps_bf = (unsigned short*)ws;                 // 4 MB
    unsigned short* repsT   = (unsigned short*)(ws + (4u << 20));  // 4 MB
    unsigned short* hid_prt = (unsigned short*)(ws + (8u << 20));  // 32 MB (16 x 2 MB)
    unsigned short* hid_bf  = (unsigned short*)(ws + (40u << 20)); // 2 MB

    reps_kernel<<<N_FEAT / NT, 256, 0, stream>>>(proj, rw, rb, cb, reps_bf, repsT);
    gemm1_kernel<<<dim3(2, 32, KSPLIT), 256, 0, stream>>>(x, repsT, hid_prt);
    reduce_kernel<<<512, 256, 0, stream>>>(hid_prt, hid_bf);
    gemm2_kernel<<<dim3(64, 32), 256, 0, stream>>>(hid_bf, reps_bf, bias, out);
}